// Round 2
// baseline (1055.826 us; speedup 1.0000x reference)
//
#include <hip/hip_runtime.h>
#include <hip/hip_bf16.h>
#include <math.h>

// Problem constants
constexpr int B_ = 16, N_ = 196, D_ = 128, Q_ = 65536;
constexpr int M_ = B_ * N_;            // 3136 query rows
constexpr float TEMP_INV = 5.0f;       // 1/0.2
constexpr float SHIFT = 5.0f;          // logits <= 1/T = 5 exactly (cosine <= 1)
// exp(5x - 5) = 2^(x*C - C), C = 5*log2(e)
constexpr float EXPC = 7.213475204444817f;

typedef __attribute__((ext_vector_type(8))) short short8;
typedef __attribute__((ext_vector_type(4))) float floatx4;

// round-to-nearest-even f32 -> bf16 (deterministic, no NaN inputs here)
__device__ inline ushort f2bf(float x) {
    union { float f; unsigned u; } v; v.f = x;
    unsigned r = (v.u + 0x7FFFu + ((v.u >> 16) & 1u)) >> 16;
    return (ushort)r;
}

// ---------------------------------------------------------------------------
// Kernel 1: L2-normalize queue rows, store bf16 [Q][128]. One wave per row.
__global__ void norm_queue_kernel(const float* __restrict__ queue,
                                  ushort* __restrict__ queue_bf) {
    int wave = threadIdx.x >> 6;
    int lane = threadIdx.x & 63;
    int row = blockIdx.x * 4 + wave;
    const float2* src = (const float2*)(queue + (size_t)row * 128);
    float2 v = src[lane];
    float ss = v.x * v.x + v.y * v.y;
#pragma unroll
    for (int off = 32; off; off >>= 1) ss += __shfl_xor(ss, off);
    float rinv = 1.0f / fmaxf(sqrtf(ss), 1e-12f);
    ushort2 o;
    o.x = f2bf(v.x * rinv);
    o.y = f2bf(v.y * rinv);
    ((ushort2*)(queue_bf + (size_t)row * 128))[lane] = o;
}

// ---------------------------------------------------------------------------
// Kernel 2: L2-normalize q rows (bf16 + f32) and k rows (f32). One wave/row.
__global__ void norm_qk_kernel(const float* __restrict__ d1,
                               const float* __restrict__ d2,
                               ushort* __restrict__ q_bf,
                               float* __restrict__ q_f,
                               float* __restrict__ k_f) {
    int wave = threadIdx.x >> 6;
    int lane = threadIdx.x & 63;
    int row = blockIdx.x * 4 + wave;          // 0..6271
    bool isQ = row < M_;
    int r = isQ ? row : row - M_;
    const float2* src = (const float2*)((isQ ? d1 : d2) + (size_t)r * 128);
    float2 v = src[lane];
    float ss = v.x * v.x + v.y * v.y;
#pragma unroll
    for (int off = 32; off; off >>= 1) ss += __shfl_xor(ss, off);
    float rinv = 1.0f / fmaxf(sqrtf(ss), 1e-12f);
    float2 o; o.x = v.x * rinv; o.y = v.y * rinv;
    if (isQ) {
        ((float2*)(q_f + (size_t)r * 128))[lane] = o;
        ushort2 ob; ob.x = f2bf(o.x); ob.y = f2bf(o.y);
        ((ushort2*)(q_bf + (size_t)r * 128))[lane] = ob;
    } else {
        ((float2*)(k_f + (size_t)r * 128))[lane] = o;
    }
}

// ---------------------------------------------------------------------------
// Kernel 3: pos_sim[b,n] = max_m dot(q_n[b,n], k_n[b,m]) * (1/T)
__global__ void possim_kernel(const float* __restrict__ q_f,
                              const float* __restrict__ k_f,
                              float* __restrict__ pos_out) {
    __shared__ __align__(16) float qs[128];
    __shared__ float red[256];
    int bn = blockIdx.x;
    int b = bn / N_;
    int t = threadIdx.x;
    if (t < 128) qs[t] = q_f[(size_t)bn * 128 + t];
    __syncthreads();
    float best = -1e30f;
    if (t < N_) {
        const float4* kr = (const float4*)(k_f + ((size_t)b * N_ + t) * 128);
        const float4* qv = (const float4*)qs;
        float dot = 0.f;
#pragma unroll
        for (int i = 0; i < 32; i++) {
            float4 kk = kr[i]; float4 qq = qv[i];
            dot += kk.x * qq.x + kk.y * qq.y + kk.z * qq.z + kk.w * qq.w;
        }
        best = dot;
    }
    red[t] = best;
    __syncthreads();
    for (int s = 128; s; s >>= 1) {
        if (t < s) red[t] = fmaxf(red[t], red[t + s]);
        __syncthreads();
    }
    if (t == 0) pos_out[bn] = red[0] * TEMP_INV;
}

// ---------------------------------------------------------------------------
// Kernel 4: neg_sim = q_n @ queue_n^T * (1/T), bf16 MFMA 16x16x32.
// RESTRUCTURED: one block per n-tile (grid=512). Block stages its 128 queue
// rows into LDS ONCE (pre-swizzled into fragment order -> contiguous 1KB
// wave ds_read_b128, zero bank conflicts, immediate offsets), then loops
// over all 49 m-tiles. A-fragments are read directly from global (q_bf is
// 784KB -> L2-resident on every XCD). NO barriers in the main loop.
// queue_bf HBM/L3 traffic: 784MB -> 16MB (read exactly once).
// Row-sum epilogue: per-(block,row) partial -> partial[bx*M_+row] (no atomics),
// or atomicAdd fallback when workspace is too small for the partial array.
constexpr int BM = 64, BN = 128;
constexpr int YT = M_ / BM;            // 49 m-tiles

template<bool USE_PARTIAL>
__global__ __launch_bounds__(256) void gemm_kernel(
        const ushort* __restrict__ q_bf, const ushort* __restrict__ queue_bf,
        float* __restrict__ neg_out, float* __restrict__ red) {
    // Bs fragment-major: [c(8)][kk(4)][lane(64)][8 bf16] = 32 KB
    __shared__ __align__(16) ushort Bs[BN * 128];
    int t = threadIdx.x;
    int colBase = blockIdx.x * BN;

    // Stage B once: LDS dest linear in j, global source pre-swizzled.
#pragma unroll
    for (int i = 0; i < 8; i++) {
        int j = t + i * 256;               // 16B-chunk index, 0..2047
        int c    = j >> 8;
        int kk   = (j >> 6) & 3;
        int l    = j & 63;
        int row    = c * 16 + (l & 15);
        int kchunk = kk * 4 + (l >> 4);    // 8-elem k-chunk
        uint4 v = *(const uint4*)(queue_bf + (size_t)(colBase + row) * 128 + kchunk * 8);
        *(uint4*)((char*)Bs + (size_t)j * 16) = v;
    }
    __syncthreads();

    int wave = t >> 6, lane = t & 63;
    int m16 = lane & 15, quad = lane >> 4;

    const ushort* aptr = q_bf + (size_t)(wave * 16 + m16) * 128 + quad * 8;
    float* outp = neg_out + (size_t)(wave * 16 + m16) * Q_ + colBase + quad * 4;
    float* pptr = red + (USE_PARTIAL ? (size_t)blockIdx.x * M_ : 0)
                      + wave * 16 + m16;

    for (int y = 0; y < YT; y++) {
        short8 a[4];
#pragma unroll
        for (int kk = 0; kk < 4; kk++)
            a[kk] = *(const short8*)(aptr + kk * 32);

        floatx4 acc[8];
#pragma unroll
        for (int c = 0; c < 8; c++) acc[c] = floatx4{0.f, 0.f, 0.f, 0.f};

#pragma unroll
        for (int kk = 0; kk < 4; kk++) {
#pragma unroll
            for (int c = 0; c < 8; c++) {
                short8 bb = *(const short8*)(Bs + ((c * 4 + kk) * 64 + lane) * 8);
                // Swapped operands: D[n][m], lane's col = m16 (its A row)
                acc[c] = __builtin_amdgcn_mfma_f32_16x16x32_bf16(bb, a[kk], acc[c], 0, 0, 0);
            }
        }

        float esum = 0.f;
#pragma unroll
        for (int c = 0; c < 8; c++) {
            floatx4 v;
#pragma unroll
            for (int r = 0; r < 4; r++) {
                float x = acc[c][r];
                v[r] = x * TEMP_INV;
                esum += exp2f(__builtin_fmaf(x, EXPC, -EXPC));
            }
            *(floatx4*)(outp + c * 16) = v;   // all 32 values belong to one row
        }
        esum += __shfl_xor(esum, 16);
        esum += __shfl_xor(esum, 32);
        if (quad == 0) {
            if constexpr (USE_PARTIAL) *pptr = esum;
            else atomicAdd(pptr, esum);
        }

        aptr += (size_t)BM * 128;
        outp += (size_t)BM * Q_;
        pptr += BM;
    }
}

// ---------------------------------------------------------------------------
// Kernel 5: per-row total = sum_bx partial + exp(pos-SHIFT);
// loss = mean(log(total) + SHIFT - pos). Grid 49 x 64 (1 wave/block).
template<bool USE_PARTIAL>
__global__ void reduce_loss_kernel(const float* __restrict__ red,
                                   const float* __restrict__ pos,
                                   float* __restrict__ out_loss) {
    int lane = threadIdx.x & 63;
    int row = blockIdx.x * 64 + lane;
    float s = 0.f;
    if constexpr (USE_PARTIAL) {
#pragma unroll 8
        for (int bx = 0; bx < Q_ / BN; bx++)
            s += red[(size_t)bx * M_ + row];
    } else {
        s = red[row];
    }
    float p = pos[row];
    float total = s + __expf(p - SHIFT);
    float term = logf(total) + SHIFT - p;
#pragma unroll
    for (int off = 32; off; off >>= 1) term += __shfl_xor(term, off);
    if (lane == 0) atomicAdd(out_loss, term * (1.0f / (float)M_));
}

// ---------------------------------------------------------------------------
extern "C" void kernel_launch(void* const* d_in, const int* in_sizes, int n_in,
                              void* d_out, int out_size, void* d_ws, size_t ws_size,
                              hipStream_t stream) {
    const float* d1    = (const float*)d_in[0];  // dense_features_1 -> q
    const float* d2    = (const float*)d_in[1];  // dense_features_2 -> k
    const float* queue = (const float*)d_in[4];

    float* out     = (float*)d_out;
    float* pos_out = out + 1;            // [3136]
    float* neg_out = out + 1 + M_;       // [3136][65536]

    char* ws = (char*)d_ws;
    size_t off = 0;
    ushort* queue_bf = (ushort*)(ws + off); off += (size_t)Q_ * 128 * 2;  // 16 MB
    ushort* q_bf     = (ushort*)(ws + off); off += (size_t)M_ * 128 * 2;  // 784 KB
    float*  q_f      = (float*)(ws + off);  off += (size_t)M_ * 128 * 4;
    float*  k_f      = (float*)(ws + off);  off += (size_t)M_ * 128 * 4;
    float*  red      = (float*)(ws + off);  // partial [512][3136] or row_sum [3136]
    size_t need_partial = off + (size_t)(Q_ / BN) * M_ * 4;
    bool useP = ws_size >= need_partial;

    hipMemsetAsync(out, 0, sizeof(float), stream);   // loss accumulator
    if (!useP) hipMemsetAsync(red, 0, M_ * sizeof(float), stream);

    norm_queue_kernel<<<Q_ / 4, 256, 0, stream>>>(queue, queue_bf);
    norm_qk_kernel<<<(2 * M_) / 4, 256, 0, stream>>>(d1, d2, q_bf, q_f, k_f);
    possim_kernel<<<M_, 256, 0, stream>>>(q_f, k_f, pos_out);

    if (useP) {
        gemm_kernel<true><<<Q_ / BN, 256, 0, stream>>>(q_bf, queue_bf, neg_out, red);
        reduce_loss_kernel<true><<<YT, 64, 0, stream>>>(red, pos_out, out);
    } else {
        gemm_kernel<false><<<Q_ / BN, 256, 0, stream>>>(q_bf, queue_bf, neg_out, red);
        reduce_loss_kernel<false><<<YT, 64, 0, stream>>>(red, pos_out, out);
    }
}